// Round 7
// baseline (421.766 us; speedup 1.0000x reference)
//
#include <hip/hip_runtime.h>

#define N_SEQ 16384
#define LSEQ  512
#define VOCAB 32000
#define ES    32
#define HS    64
#define LDH   72    // padded f16 stride per m-row in LDS
#define TS    18    // tok stride in u16 (transposed [t][s], odd dword stride)

#define SC_RZ (-1.4426950408889634f)   // -log2(e): folded into r,z weights
#define SC_N  (-2.8853900817779268f)   // -2*log2(e): folded into n weights

typedef _Float16 v8h __attribute__((ext_vector_type(8)));
typedef float    v4f __attribute__((ext_vector_type(4)));

// ---------------- K1 (fused prep): lengths | emb->f16 | weight packs --------
#define NLB (N_SEQ / 4)            // 4096 blocks: wave-per-row length count
#define NEB (VOCAB * ES / 2048)    // 500 blocks: vectorized emb convert (8/thr)
__global__ __launch_bounds__(256) void k_prep(const int* __restrict__ x,
                                              const float* __restrict__ emb,
                                              const float* __restrict__ whh,
                                              const float* __restrict__ wih,
                                              int* __restrict__ len,
                                              int* __restrict__ hist,
                                              _Float16* __restrict__ ef,
                                              _Float16* __restrict__ wpk,
                                              _Float16* __restrict__ wpe){
  int b = blockIdx.x;
  if (b < NLB){                               // ---- lengths: coalesced count
    int row  = b * 4 + (threadIdx.x >> 6);
    int lane = threadIdx.x & 63;
    const int4* xr = (const int4*)(x + (size_t)row * LSEQ);
    int cnt = 0;
    #pragma unroll
    for (int i = 0; i < 2; ++i){
      int4 v = xr[lane + i*64];
      cnt += (v.x != 0) + (v.y != 0) + (v.z != 0) + (v.w != 0);
    }
    #pragma unroll
    for (int d = 1; d < 64; d <<= 1) cnt += __shfl_xor(cnt, d, 64);
    if (lane == 0){ len[row] = cnt; atomicAdd(&hist[cnt], 1); }
  } else if (b < NLB + NEB){                  // ---- emb f32 -> f16, 8/thread
    int i = ((b - NLB) * 256 + threadIdx.x) * 8;
    float4 f0 = *(const float4*)(emb + i);
    float4 f1 = *(const float4*)(emb + i + 4);
    v8h o;
    o[0] = (_Float16)f0.x; o[1] = (_Float16)f0.y;
    o[2] = (_Float16)f0.z; o[3] = (_Float16)f0.w;
    o[4] = (_Float16)f1.x; o[5] = (_Float16)f1.y;
    o[6] = (_Float16)f1.z; o[7] = (_Float16)f1.w;
    *(v8h*)(ef + i) = o;
  } else {                                    // ---- weight packs (9 blocks)
    int tid = (b - NLB - NEB) * 256 + threadIdx.x;
    if (tid < 1536){                          // w_hh: 24 frags (K=64: 2 frags)
      int f = tid >> 6, l = tid & 63;
      int jt = f >> 1, kf = f & 1;
      float sc = (jt < 8) ? SC_RZ : SC_N;     // exp2-arg scale folded in
      #pragma unroll
      for (int i = 0; i < 8; ++i){
        int row = jt * 16 + (l & 15);
        int col = kf * 32 + (l >> 4) * 8 + i;
        wpk[(size_t)tid * 8 + i] = (_Float16)(sc * whh[row * HS + col]);
      }
    } else if (tid < 1536 + 768){             // w_ih: 12 frags (K=32)
      int t2 = tid - 1536;
      int tile = t2 >> 6, l = t2 & 63;
      float sc = ((tile >> 2) < 2) ? SC_RZ : SC_N;
      #pragma unroll
      for (int i = 0; i < 8; ++i){
        int row = tile * 16 + (l & 15);
        int col = (l >> 4) * 8 + i;
        wpe[(size_t)t2 * 8 + i] = (_Float16)(sc * wih[row * ES + col]);
      }
    }
  }
}

// ---------------- K2: fused scan + scatter ----------------------------------
__global__ __launch_bounds__(1024) void k_scatter(const int* __restrict__ hist,
                                                  const int* __restrict__ len,
                                                  int* __restrict__ gcnt,
                                                  int* __restrict__ perm){
  __shared__ int buf[1024];
  __shared__ int offs[513];
  int i = threadIdx.x;
  buf[i] = (i < 513) ? hist[i] : 0;
  __syncthreads();
  for (int d = 1; d < 1024; d <<= 1){
    int v = (i >= d) ? buf[i - d] : 0;
    __syncthreads();
    buf[i] += v;
    __syncthreads();
  }
  if (i < 513) offs[i] = (i == 0) ? 0 : buf[i - 1];
  __syncthreads();
  int s = blockIdx.x * 1024 + i;
  int l = len[s];
  int pos = offs[l] + atomicAdd(&gcnt[l], 1);
  perm[pos] = s;                              // ascending by length
}

// ---------------- K3: recurrence (DUAL-GROUP per block for pipe overlap) ----
// R1's counters: VALUBusy+MfmaUtil = 99.8% -> lockstep barriers serialize the
// VALU and matrix pipes (all waves in the same phase; gates depend on MFMAs).
// Wall == VALU-issue + MFMA-pipe, serial. Fix: each 256-thr block processes
// TWO adjacent-sorted groups A,B (32 seqs); per round [A-step][B-step] then
// one lgkm+barrier. Within a wave, B's gh-MFMAs overlap A's gate VALU (and
// vice versa) -> the 159k cyc/SIMD of matrix-pipe time hides under the 417k
// of VALU issue. 512 blocks = 2 blocks/CU = 2 waves/SIMD (R5's mechanism at
// the right residency). Adjacent pairing -> A,B finish together; serpentine
// block->CU map keeps per-CU durations complementary.
__global__ __launch_bounds__(256, 2) void k_gru(
    const int* __restrict__ x, const _Float16* __restrict__ ef,
    const _Float16* __restrict__ wpk, const _Float16* __restrict__ wpe,
    const float* __restrict__ bih, const float* __restrict__ bhh,
    const int* __restrict__ perm, const int* __restrict__ len,
    float* __restrict__ out)
{
  __shared__ __align__(16) _Float16 hbA[2][16 * LDH];
  __shared__ __align__(16) _Float16 hbB[2][16 * LDH];
  __shared__ unsigned short tokA[(LSEQ + 2) * TS];
  __shared__ unsigned short tokB[(LSEQ + 2) * TS];
  int qt   = threadIdx.x >> 6;
  int w = blockIdx.x >> 8, cq = blockIdx.x & 255;
  int rank = w * 256 + ((w & 1) ? (255 - cq) : cq);   // 0..511
  int grpA = 2 * rank;                                // ascending-sorted pair
  int grpB = 2 * rank + 1;
  int lane = threadIdx.x & 63;
  int q = lane >> 4, c = lane & 15;
  int uu = qt*16 + c;

  v8h bfh[3][2], bfe[3];
  #pragma unroll
  for (int g = 0; g < 3; ++g){
    int tile = g*4 + qt;
    #pragma unroll
    for (int kf = 0; kf < 2; ++kf)
      bfh[g][kf] = *(const v8h*)(wpk + ((size_t)(tile*2 + kf)*64 + lane)*8);
    bfe[g] = *(const v8h*)(wpe + ((size_t)tile*64 + lane)*8);
  }

  int sqA[4], lnA[4], sqB[4], lnB[4];
  #pragma unroll
  for (int r = 0; r < 4; ++r){
    int sa = perm[grpA * 16 + q*4 + r];
    int sb = perm[grpB * 16 + q*4 + r];
    sqA[r] = sa; lnA[r] = len[sa];
    sqB[r] = sb; lnB[r] = len[sb];
  }
  float br  = SC_RZ * (bih[uu]      + bhh[uu]);
  float bz  = SC_RZ * (bih[HS + uu] + bhh[HS + uu]);
  float ben = SC_N  *  bih[2*HS + uu];
  float bhn = SC_N  *  bhh[2*HS + uu];
  v4f brq  = {br, br, br, br};
  v4f bzq  = {bz, bz, bz, bz};
  v4f benq = {ben, ben, ben, ben};
  v4f bhnq = {bhn, bhn, bhn, bhn};

  float hA[4], hB[4];
  #pragma unroll
  for (int r = 0; r < 4; ++r){ hA[r] = 0.f; hB[r] = 0.f; }

  for (int i = threadIdx.x; i < 16*LDH; i += 256){
    hbA[0][i] = (_Float16)0.f;
    hbB[0][i] = (_Float16)0.f;
  }

  // stage tokens transposed for both groups (coalesced global reads)
  for (int j = threadIdx.x; j < 16*LSEQ; j += 256){
    int s = j >> 9, tt = j & (LSEQ-1);
    tokA[tt*TS + s] = (unsigned short)x[(size_t)perm[grpA*16 + s] * LSEQ + tt];
    tokB[tt*TS + s] = (unsigned short)x[(size_t)perm[grpB*16 + s] * LSEQ + tt];
  }
  if (threadIdx.x < 64){                      // zero pad rows 512,513
    int g = threadIdx.x >> 5, rr = (threadIdx.x >> 4) & 1, s = threadIdx.x & 15;
    (g ? tokB : tokA)[(LSEQ + rr)*TS + s] = 0;
  }
  __syncthreads();

  int tmax = 0, tmin = LSEQ;
  #pragma unroll
  for (int r = 0; r < 4; ++r){
    tmax = max(tmax, max(lnA[r], lnB[r]));
    tmin = min(tmin, min(lnA[r], lnB[r]));
  }
  tmax = max(tmax, __shfl_xor(tmax, 16, 64));
  tmax = max(tmax, __shfl_xor(tmax, 32, 64));
  tmin = min(tmin, __shfl_xor(tmin, 16, 64));
  tmin = min(tmin, __shfl_xor(tmin, 32, 64));

  v8h aecA, aenA, aecB, aenB;         // emb frags (ping/pong per group)
  v4f praA, prbA, pzaA, pzbA, deaA, debA;
  v4f praB, prbB, pzaB, pzbB, deaB, debB;
  {
    int tk0 = tokA[0*TS + c];
    aecA = *(const v8h*)(ef + (size_t)tk0 * ES + q*8);
    praA = __builtin_amdgcn_mfma_f32_16x16x32_f16(aecA, bfe[0], brq,  0,0,0);
    pzaA = __builtin_amdgcn_mfma_f32_16x16x32_f16(aecA, bfe[1], bzq,  0,0,0);
    deaA = __builtin_amdgcn_mfma_f32_16x16x32_f16(aecA, bfe[2], benq, 0,0,0);
    int tk1 = tokA[1*TS + c];
    aenA = *(const v8h*)(ef + (size_t)tk1 * ES + q*8);
    int tk0b = tokB[0*TS + c];
    aecB = *(const v8h*)(ef + (size_t)tk0b * ES + q*8);
    praB = __builtin_amdgcn_mfma_f32_16x16x32_f16(aecB, bfe[0], brq,  0,0,0);
    pzaB = __builtin_amdgcn_mfma_f32_16x16x32_f16(aecB, bfe[1], bzq,  0,0,0);
    deaB = __builtin_amdgcn_mfma_f32_16x16x32_f16(aecB, bfe[2], benq, 0,0,0);
    int tk1b = tokB[1*TS + c];
    aenB = *(const v8h*)(ef + (size_t)tk1b * ES + q*8);
  }

  // One group's full step, NO barrier (R1's proven step body verbatim:
  // 2-deep MFMA accumulate, scalar gates, write after gates, gx+emb last).
  #define GRU_PHASE(TOK, HB, H, LN, PRR, PRZ, DEN, PRRn, PRZn, DENn, ACONS, ALOAD, FREEZE, RB, WB) \
  {                                                                            \
    int tkn = TOK[(t + 2)*TS + c];                                             \
    v8h a0 = *(const v8h*)(&HB[RB][c*LDH + q*8]);                              \
    v8h a1 = *(const v8h*)(&HB[RB][c*LDH + 32 + q*8]);                         \
    v4f zr  = __builtin_amdgcn_mfma_f32_16x16x32_f16(a1, bfh[0][1], PRR, 0,0,0);\
    v4f Dr  = __builtin_amdgcn_mfma_f32_16x16x32_f16(a0, bfh[0][0], zr,  0,0,0);\
    v4f zz  = __builtin_amdgcn_mfma_f32_16x16x32_f16(a1, bfh[1][1], PRZ, 0,0,0);\
    v4f Dz  = __builtin_amdgcn_mfma_f32_16x16x32_f16(a0, bfh[1][0], zz,  0,0,0);\
    v4f zh  = __builtin_amdgcn_mfma_f32_16x16x32_f16(a1, bfh[2][1], bhnq,0,0,0);\
    v4f Dhn = __builtin_amdgcn_mfma_f32_16x16x32_f16(a0, bfh[2][0], zh,  0,0,0);\
    _Pragma("unroll")                                                          \
    for (int r = 0; r < 4; ++r){                                               \
      float rg   = __builtin_amdgcn_rcpf(1.f + __builtin_amdgcn_exp2f(Dr[r])); \
      float zg   = __builtin_amdgcn_rcpf(1.f + __builtin_amdgcn_exp2f(Dz[r])); \
      float te   = __builtin_amdgcn_exp2f(DEN[r] + rg * Dhn[r]);               \
      float ng   = fmaf(2.f, __builtin_amdgcn_rcpf(1.f + te), -1.f);           \
      float hnew = ng + zg * (H[r] - ng);                                      \
      H[r]       = (FREEZE && t >= LN[r]) ? H[r] : hnew;                       \
    }                                                                          \
    PRRn = __builtin_amdgcn_mfma_f32_16x16x32_f16(ACONS, bfe[0], brq,  0,0,0); \
    PRZn = __builtin_amdgcn_mfma_f32_16x16x32_f16(ACONS, bfe[1], bzq,  0,0,0); \
    DENn = __builtin_amdgcn_mfma_f32_16x16x32_f16(ACONS, bfe[2], benq, 0,0,0); \
    ALOAD = *(const v8h*)(ef + (size_t)tkn * ES + q*8);  /* emb t+2 */         \
    _Pragma("unroll")                                                          \
    for (int r = 0; r < 4; ++r)                                                \
      HB[WB][(q*4 + r)*LDH + uu] = (_Float16)H[r];                             \
  }

  #define ROUND_EVEN(FREEZE)                                                   \
    GRU_PHASE(tokA, hbA, hA, lnA, praA,pzaA,deaA, prbA,pzbA,debA, aenA, aecA, FREEZE, 0, 1); \
    GRU_PHASE(tokB, hbB, hB, lnB, praB,pzaB,deaB, prbB,pzbB,debB, aenB, aecB, FREEZE, 0, 1); \
    asm volatile("s_waitcnt lgkmcnt(0)" ::: "memory");                         \
    __builtin_amdgcn_s_barrier();                                              \
    asm volatile("" ::: "memory");

  #define ROUND_ODD(FREEZE)                                                    \
    GRU_PHASE(tokA, hbA, hA, lnA, prbA,pzbA,debA, praA,pzaA,deaA, aecA, aenA, FREEZE, 1, 0); \
    GRU_PHASE(tokB, hbB, hB, lnB, prbB,pzbB,debB, praB,pzaB,deaB, aecB, aenB, FREEZE, 1, 0); \
    asm volatile("s_waitcnt lgkmcnt(0)" ::: "memory");                         \
    __builtin_amdgcn_s_barrier();                                              \
    asm volatile("" ::: "memory");

  int t = 0;
  for (; t + 1 < tmin; ){   // no-freeze main loop
    ROUND_EVEN(0); ++t;
    ROUND_ODD(0);  ++t;
  }
  for (; t + 1 < tmax; ){   // freeze tail (adjacent pairing -> short)
    ROUND_EVEN(1); ++t;
    ROUND_ODD(1);  ++t;
  }
  if (t < tmax){
    ROUND_EVEN(1); ++t;
  }
  #undef ROUND_EVEN
  #undef ROUND_ODD
  #undef GRU_PHASE

  #pragma unroll
  for (int r = 0; r < 4; ++r){
    out[(size_t)sqA[r] * HS + uu] = hA[r];
    out[(size_t)sqB[r] * HS + uu] = hB[r];
  }
}

extern "C" void kernel_launch(void* const* d_in, const int* in_sizes, int n_in,
                              void* d_out, int out_size, void* d_ws, size_t ws_size,
                              hipStream_t stream){
  const int*   x   = (const int*)  d_in[0];
  const float* emb = (const float*)d_in[1];
  const float* wih = (const float*)d_in[2];
  const float* whh = (const float*)d_in[3];
  const float* bih = (const float*)d_in[4];
  const float* bhh = (const float*)d_in[5];
  float* out = (float*)d_out;

  char* ws = (char*)d_ws;
  size_t off = 0;
  _Float16* ef  = (_Float16*)(ws + off);  off += (size_t)VOCAB * ES * sizeof(_Float16);
  _Float16* wpk = (_Float16*)(ws + off);  off += (size_t)24 * 64 * 8 * sizeof(_Float16);
  _Float16* wpe = (_Float16*)(ws + off);  off += (size_t)12 * 64 * 8 * sizeof(_Float16);
  off = (off + 255) & ~(size_t)255;
  int* len  = (int*)(ws + off);           off += (size_t)N_SEQ * sizeof(int);
  int* perm = (int*)(ws + off);           off += (size_t)N_SEQ * sizeof(int);
  int* hist = (int*)(ws + off);           off += 513 * sizeof(int);
  int* gcnt = (int*)(ws + off);           off += 513 * sizeof(int);

  hipMemsetAsync(hist, 0, 2 * 513 * sizeof(int), stream);   // hist + gcnt
  k_prep   <<<NLB + NEB + 9, 256, 0, stream>>>(x, emb, whh, wih, len, hist, ef, wpk, wpe);
  k_scatter<<<N_SEQ / 1024, 1024, 0, stream>>>(hist, len, gcnt, perm);
  k_gru    <<<512, 256, 0, stream>>>(x, ef, wpk, wpe, bih, bhh, perm, len, out);
}

// Round 9
// 299.143 us; speedup vs baseline: 1.4099x; 1.4099x over previous
//
#include <hip/hip_runtime.h>

#define N_SEQ 16384
#define LSEQ  512
#define VOCAB 32000
#define ES    32
#define HS    64
#define LDH   72    // padded f16 stride per m-row in LDS
#define TS    18    // tok stride in u16 (transposed [t][s], odd dword stride)

#define SC_RZ (-1.4426950408889634f)   // -log2(e): folded into r,z weights
#define SC_N  (-2.8853900817779268f)   // -2*log2(e): folded into n weights

typedef _Float16 v8h __attribute__((ext_vector_type(8)));
typedef float    v4f __attribute__((ext_vector_type(4)));

// ---------------- K1 (fused prep): lengths | emb->f16 | packs | gcnt=0 ------
// hist/memset eliminated: k_scatter builds its own histogram from len[];
// gcnt zeroed here (only consumed by k_scatter -> no race).
// R8 BUGFIX: gcnt zeroing used `if (tid < 513)` with a 256-thread block ->
// gcnt[256..512] stayed garbage -> OOB perm writes -> crash. Strided loop now.
#define NLB (N_SEQ / 4)            // 4096 blocks: wave-per-row length count
#define NEB (VOCAB * ES / 2048)    // 500 blocks: vectorized emb convert (8/thr)
__global__ __launch_bounds__(256) void k_prep(const int* __restrict__ x,
                                              const float* __restrict__ emb,
                                              const float* __restrict__ whh,
                                              const float* __restrict__ wih,
                                              int* __restrict__ len,
                                              int* __restrict__ gcnt,
                                              _Float16* __restrict__ ef,
                                              _Float16* __restrict__ wpk,
                                              _Float16* __restrict__ wpe){
  int b = blockIdx.x;
  if (b < NLB){                               // ---- lengths: coalesced count
    int row  = b * 4 + (threadIdx.x >> 6);
    int lane = threadIdx.x & 63;
    const int4* xr = (const int4*)(x + (size_t)row * LSEQ);
    int cnt = 0;
    #pragma unroll
    for (int i = 0; i < 2; ++i){
      int4 v = xr[lane + i*64];
      cnt += (v.x != 0) + (v.y != 0) + (v.z != 0) + (v.w != 0);
    }
    #pragma unroll
    for (int d = 1; d < 64; d <<= 1) cnt += __shfl_xor(cnt, d, 64);
    if (lane == 0) len[row] = cnt;
  } else if (b < NLB + NEB){                  // ---- emb f32 -> f16, 8/thread
    int i = ((b - NLB) * 256 + threadIdx.x) * 8;
    float4 f0 = *(const float4*)(emb + i);
    float4 f1 = *(const float4*)(emb + i + 4);
    v8h o;
    o[0] = (_Float16)f0.x; o[1] = (_Float16)f0.y;
    o[2] = (_Float16)f0.z; o[3] = (_Float16)f0.w;
    o[4] = (_Float16)f1.x; o[5] = (_Float16)f1.y;
    o[6] = (_Float16)f1.z; o[7] = (_Float16)f1.w;
    *(v8h*)(ef + i) = o;
  } else if (b < NLB + NEB + 6){              // ---- pack w_hh (24 frags)
    int tid = (b - NLB - NEB) * 256 + threadIdx.x;
    int f = tid >> 6, l = tid & 63;
    int jt = f >> 1, kf = f & 1;
    float sc = (jt < 8) ? SC_RZ : SC_N;       // exp2-arg scale folded in
    #pragma unroll
    for (int i = 0; i < 8; ++i){
      int row = jt * 16 + (l & 15);
      int col = kf * 32 + (l >> 4) * 8 + i;
      wpk[(size_t)tid * 8 + i] = (_Float16)(sc * whh[row * HS + col]);
    }
  } else if (b < NLB + NEB + 9){              // ---- pack w_ih (12 frags)
    int t2 = (b - NLB - NEB - 6) * 256 + threadIdx.x;
    int tile = t2 >> 6, l = t2 & 63;
    float sc = ((tile >> 2) < 2) ? SC_RZ : SC_N;
    #pragma unroll
    for (int i = 0; i < 8; ++i){
      int row = tile * 16 + (l & 15);
      int col = (l >> 4) * 8 + i;
      wpe[(size_t)t2 * 8 + i] = (_Float16)(sc * wih[row * ES + col]);
    }
  } else {                                    // ---- zero gcnt[0..512] (strided!)
    for (int i = threadIdx.x; i < 513; i += 256) gcnt[i] = 0;
  }
}

// ---------------- K2: self-contained scatter (own hist from len[]) ----------
// 16 blocks x 1024: each block builds the FULL histogram from len (16 reads /
// thread, L2-hot), scans it in LDS, then scatters its 1024 seq ids via the
// global per-bucket counters (gcnt zeroed by k_prep).
__global__ __launch_bounds__(1024) void k_scatter(const int* __restrict__ len,
                                                  int* __restrict__ gcnt,
                                                  int* __restrict__ perm){
  __shared__ int buf[1024];
  __shared__ int offs[513];
  int i = threadIdx.x;
  buf[i] = 0;
  __syncthreads();
  #pragma unroll
  for (int k = 0; k < 16; ++k)
    atomicAdd(&buf[len[k * 1024 + i]], 1);    // LDS histogram (513 buckets)
  __syncthreads();
  for (int d = 1; d < 1024; d <<= 1){         // inclusive scan
    int v = (i >= d) ? buf[i - d] : 0;
    __syncthreads();
    buf[i] += v;
    __syncthreads();
  }
  if (i < 513) offs[i] = (i == 0) ? 0 : buf[i - 1];
  __syncthreads();
  int s = blockIdx.x * 1024 + i;
  int l = len[s];
  int pos = offs[l] + atomicAdd(&gcnt[l], 1);
  perm[pos] = s;                              // ascending by length
}

// ---------------- K3: recurrence (R1 champion schedule + setprio) -----------
// R3-R7 ledger: every restructure (LPT steal, chain-pack, block fusion,
// dual-group) loses to this schedule; R1's pipes account for 100% of wall
// (VALU 174us + MFMA 71us, serial). k_gru kept byte-identical to the 245us
// version EXCEPT s_setprio(1) around the MFMA clusters (T5: positive in the
// drifting-independent-blocks regime, which this is).
__global__ __launch_bounds__(256, 4) void k_gru(
    const int* __restrict__ x, const _Float16* __restrict__ ef,
    const _Float16* __restrict__ wpk, const _Float16* __restrict__ wpe,
    const float* __restrict__ bih, const float* __restrict__ bhh,
    const int* __restrict__ perm, const int* __restrict__ len,
    float* __restrict__ out)
{
  __shared__ __align__(16) _Float16 hb[2][16 * LDH];
  __shared__ unsigned short tok[(LSEQ + 2) * TS];   // transposed tokens
  int qt   = threadIdx.x >> 6;
  int w = blockIdx.x >> 8, cq = blockIdx.x & 255;
  int rank = w * 256 + ((w & 1) ? (255 - cq) : cq);   // 0 = longest
  int grp  = 1023 - rank;                             // ascending-sorted index
  int lane = threadIdx.x & 63;
  int q = lane >> 4, c = lane & 15;
  int uu = qt*16 + c;

  v8h bfh[3][2], bfe[3];
  #pragma unroll
  for (int g = 0; g < 3; ++g){
    int tile = g*4 + qt;
    #pragma unroll
    for (int kf = 0; kf < 2; ++kf)
      bfh[g][kf] = *(const v8h*)(wpk + ((size_t)(tile*2 + kf)*64 + lane)*8);
    bfe[g] = *(const v8h*)(wpe + ((size_t)tile*64 + lane)*8);
  }

  int sq[4], ln[4];
  #pragma unroll
  for (int r = 0; r < 4; ++r){
    int s = perm[grp * 16 + q*4 + r];
    sq[r] = s;
    ln[r] = len[s];
  }
  float br  = SC_RZ * (bih[uu]      + bhh[uu]);
  float bz  = SC_RZ * (bih[HS + uu] + bhh[HS + uu]);
  float ben = SC_N  *  bih[2*HS + uu];
  float bhn = SC_N  *  bhh[2*HS + uu];
  v4f brq  = {br, br, br, br};
  v4f bzq  = {bz, bz, bz, bz};
  v4f benq = {ben, ben, ben, ben};
  v4f bhnq = {bhn, bhn, bhn, bhn};

  float h[4];
  #pragma unroll
  for (int r = 0; r < 4; ++r) h[r] = 0.f;

  for (int i = threadIdx.x; i < 16*LDH; i += 256) hb[0][i] = (_Float16)0.f;

  // stage tokens transposed: global reads coalesced; LDS writes 2-way (free).
  for (int j = threadIdx.x; j < 16*LSEQ; j += 256){
    int s = j >> 9, tt = j & (LSEQ-1);
    tok[tt*TS + s] = (unsigned short)x[(size_t)perm[grp*16 + s] * LSEQ + tt];
  }
  if (threadIdx.x < 32){                      // zero rows 512,513 (t+2 lookahead)
    tok[(LSEQ + (threadIdx.x >> 4))*TS + (threadIdx.x & 15)] = 0;
  }
  __syncthreads();

  int tmax = max(max(ln[0], ln[1]), max(ln[2], ln[3]));
  tmax = max(tmax, __shfl_xor(tmax, 16, 64));
  tmax = max(tmax, __shfl_xor(tmax, 32, 64));
  int tmin = min(min(ln[0], ln[1]), min(ln[2], ln[3]));
  tmin = min(tmin, __shfl_xor(tmin, 16, 64));
  tmin = min(tmin, __shfl_xor(tmin, 32, 64));

  v8h aec, aen;                       // emb frags: consume one, load the other
  v4f pra, prb, pza, pzb, dea, deb;   // e-partials: r, z, n (ping/pong)
  {
    int tk0 = tok[0*TS + c];
    aec = *(const v8h*)(ef + (size_t)tk0 * ES + q*8);
    pra = __builtin_amdgcn_mfma_f32_16x16x32_f16(aec, bfe[0], brq,  0,0,0);
    pza = __builtin_amdgcn_mfma_f32_16x16x32_f16(aec, bfe[1], bzq,  0,0,0);
    dea = __builtin_amdgcn_mfma_f32_16x16x32_f16(aec, bfe[2], benq, 0,0,0);
    int tk1 = tok[1*TS + c];
    aen = *(const v8h*)(ef + (size_t)tk1 * ES + q*8);   // emb for t=1
  }

  // ACONS = emb(t+1), loaded one full step ago; ALOAD <- emb(t+2) this step.
  #define GRU_STEP(FREEZE, ACONS, ALOAD, PRR, PRZ, DEN, PRRn, PRZn, DENn, RB, WB) \
  {                                                                            \
    int tkn = tok[(t + 2)*TS + c];                                             \
    v8h a0 = *(const v8h*)(&hb[RB][c*LDH + q*8]);                              \
    v8h a1 = *(const v8h*)(&hb[RB][c*LDH + 32 + q*8]);                         \
    __builtin_amdgcn_s_setprio(1);                                             \
    v4f zr  = __builtin_amdgcn_mfma_f32_16x16x32_f16(a1, bfh[0][1], PRR, 0,0,0);\
    v4f Dr  = __builtin_amdgcn_mfma_f32_16x16x32_f16(a0, bfh[0][0], zr,  0,0,0);\
    v4f zz  = __builtin_amdgcn_mfma_f32_16x16x32_f16(a1, bfh[1][1], PRZ, 0,0,0);\
    v4f Dz  = __builtin_amdgcn_mfma_f32_16x16x32_f16(a0, bfh[1][0], zz,  0,0,0);\
    v4f zh  = __builtin_amdgcn_mfma_f32_16x16x32_f16(a1, bfh[2][1], bhnq,0,0,0);\
    v4f Dhn = __builtin_amdgcn_mfma_f32_16x16x32_f16(a0, bfh[2][0], zh,  0,0,0);\
    __builtin_amdgcn_s_setprio(0);                                             \
    _Pragma("unroll")                                                          \
    for (int r = 0; r < 4; ++r){                                               \
      float rg   = __builtin_amdgcn_rcpf(1.f + __builtin_amdgcn_exp2f(Dr[r])); \
      float zg   = __builtin_amdgcn_rcpf(1.f + __builtin_amdgcn_exp2f(Dz[r])); \
      float te   = __builtin_amdgcn_exp2f(DEN[r] + rg * Dhn[r]);               \
      float ng   = fmaf(2.f, __builtin_amdgcn_rcpf(1.f + te), -1.f);           \
      float hnew = ng + zg * (h[r] - ng);                                      \
      h[r]       = (FREEZE && t >= ln[r]) ? h[r] : hnew;                       \
    }                                                                          \
    __builtin_amdgcn_s_setprio(1);                                             \
    PRRn = __builtin_amdgcn_mfma_f32_16x16x32_f16(ACONS, bfe[0], brq,  0,0,0); \
    PRZn = __builtin_amdgcn_mfma_f32_16x16x32_f16(ACONS, bfe[1], bzq,  0,0,0); \
    DENn = __builtin_amdgcn_mfma_f32_16x16x32_f16(ACONS, bfe[2], benq, 0,0,0); \
    __builtin_amdgcn_s_setprio(0);                                             \
    ALOAD = *(const v8h*)(ef + (size_t)tkn * ES + q*8);  /* emb t+2 */         \
    _Pragma("unroll")                                                          \
    for (int r = 0; r < 4; ++r)                                                \
      hb[WB][(q*4 + r)*LDH + uu] = (_Float16)h[r];                             \
    asm volatile("s_waitcnt lgkmcnt(0)" ::: "memory");                         \
    __builtin_amdgcn_s_barrier();                                              \
    asm volatile("" ::: "memory");                                             \
  }

  int t = 0;
  for (; t + 1 < tmin; ){   // no-freeze main loop (t and t+1 both < all ln)
    GRU_STEP(0, aen, aec, pra, pza, dea, prb, pzb, deb, 0, 1); ++t;
    GRU_STEP(0, aec, aen, prb, pzb, deb, pra, pza, dea, 1, 0); ++t;
  }
  for (; t + 1 < tmax; ){   // tail pairs with freeze (parity preserved)
    GRU_STEP(1, aen, aec, pra, pza, dea, prb, pzb, deb, 0, 1); ++t;
    GRU_STEP(1, aec, aen, prb, pzb, deb, pra, pza, dea, 1, 0); ++t;
  }
  if (t < tmax){
    GRU_STEP(1, aen, aec, pra, pza, dea, prb, pzb, deb, 0, 1); ++t;
  }
  #undef GRU_STEP

  #pragma unroll
  for (int r = 0; r < 4; ++r)
    out[(size_t)sq[r] * HS + uu] = h[r];
}

extern "C" void kernel_launch(void* const* d_in, const int* in_sizes, int n_in,
                              void* d_out, int out_size, void* d_ws, size_t ws_size,
                              hipStream_t stream){
  const int*   x   = (const int*)  d_in[0];
  const float* emb = (const float*)d_in[1];
  const float* wih = (const float*)d_in[2];
  const float* whh = (const float*)d_in[3];
  const float* bih = (const float*)d_in[4];
  const float* bhh = (const float*)d_in[5];
  float* out = (float*)d_out;

  char* ws = (char*)d_ws;
  size_t off = 0;
  _Float16* ef  = (_Float16*)(ws + off);  off += (size_t)VOCAB * ES * sizeof(_Float16);
  _Float16* wpk = (_Float16*)(ws + off);  off += (size_t)24 * 64 * 8 * sizeof(_Float16);
  _Float16* wpe = (_Float16*)(ws + off);  off += (size_t)12 * 64 * 8 * sizeof(_Float16);
  off = (off + 255) & ~(size_t)255;
  int* len  = (int*)(ws + off);           off += (size_t)N_SEQ * sizeof(int);
  int* perm = (int*)(ws + off);           off += (size_t)N_SEQ * sizeof(int);
  int* gcnt = (int*)(ws + off);           off += 513 * sizeof(int);

  k_prep   <<<NLB + NEB + 10, 256, 0, stream>>>(x, emb, whh, wih, len, gcnt, ef, wpk, wpe);
  k_scatter<<<N_SEQ / 1024, 1024, 0, stream>>>(len, gcnt, perm);
  k_gru    <<<N_SEQ / 16,    256, 0, stream>>>(x, ef, wpk, wpe, bih, bhh, perm, len, out);
}